// Round 3
// baseline (340.064 us; speedup 1.0000x reference)
//
#include <hip/hip_runtime.h>
#include <hip/hip_bf16.h>

// NeuralODE: y_{s+1} = y_s + DT*(tanh(y W1 + b1) W2 + b2), 250 steps,
// snapshot every 5 -> out[8192][51][128] fp32.
//
// R4: hidden-space recurrence: z = y W1 + b1, W21 = W2 W1 (fp32 prologue),
//   substep:  a = tanh(z); z += DT*(a @ W21 + c),  c = b2 W1
//   interval: y += DT*(S @ W2 + 5 b2), S = sum of 5 a's
// R5: BARRIER-FREE single-wave design. One 64-thread block owns one 16-row
// tile and the FULL 64-dim hidden state (z in C-layout regs). The per-substep
// C-layout -> B-fragment transpose of a is within-wave via a private 2KB LDS
// buffer (4x ds_write_b64 + 2x ds_read_b128, XOR-block-swizzled, ordered by
// lgkmcnt only -- no __syncthreads anywhere). 512 blocks = 2 waves/CU.
// W2 fragments + 5*b2 cached in LDS (snapshot-only reads). R4's ~1200cy
// substep was dominated by 4-wave barrier convergence; this removes it.

typedef __attribute__((ext_vector_type(8))) short bf16x8;   // 8 bf16 = 4 VGPRs
typedef __attribute__((ext_vector_type(4))) float floatx4;

__device__ float g_w21[64 * 64 + 64];   // W21[hin][hout] (64x64) then c[hout]

static __device__ __forceinline__ short f2bf(float f) {
    return __builtin_bit_cast(short, (__bf16)f);            // RNE, HW cvt
}

static __device__ __forceinline__ unsigned pack2(float a, float b) {
    unsigned short lo = __builtin_bit_cast(unsigned short, (__bf16)a);
    unsigned short hi = __builtin_bit_cast(unsigned short, (__bf16)b);
    return (unsigned)lo | ((unsigned)hi << 16);
}

static __device__ __forceinline__ float tanh_fast(float x) {
    // tanh(x) = 1 - 2/(1+e^{2x}); exp->inf saturates to +1, exp->0 to -1.
    float e = __expf(2.0f * x);
    return 1.0f - 2.0f * __builtin_amdgcn_rcpf(1.0f + e);
}

// ---- prologue: W21 = W2 @ W1 (fp32), c = b2 @ W1 ----
__global__ __launch_bounds__(64) void precompute_kernel(
    const float* __restrict__ W1, const float* __restrict__ W2,
    const float* __restrict__ b2)
{
    const int hout = threadIdx.x;   // 0..63
    const int hin  = blockIdx.x;    // 0..64 (64 == bias row)
    float a0 = 0.f, a1 = 0.f, a2 = 0.f, a3 = 0.f;
    if (hin < 64) {
        #pragma unroll 4
        for (int d = 0; d < 128; d += 4) {
            a0 = fmaf(W2[hin * 128 + d + 0], W1[(d + 0) * 64 + hout], a0);
            a1 = fmaf(W2[hin * 128 + d + 1], W1[(d + 1) * 64 + hout], a1);
            a2 = fmaf(W2[hin * 128 + d + 2], W1[(d + 2) * 64 + hout], a2);
            a3 = fmaf(W2[hin * 128 + d + 3], W1[(d + 3) * 64 + hout], a3);
        }
        g_w21[hin * 64 + hout] = (a0 + a1) + (a2 + a3);
    } else {
        #pragma unroll 4
        for (int d = 0; d < 128; d += 4) {
            a0 = fmaf(b2[d + 0], W1[(d + 0) * 64 + hout], a0);
            a1 = fmaf(b2[d + 1], W1[(d + 1) * 64 + hout], a1);
            a2 = fmaf(b2[d + 2], W1[(d + 2) * 64 + hout], a2);
            a3 = fmaf(b2[d + 3], W1[(d + 3) * 64 + hout], a3);
        }
        g_w21[4096 + hout] = (a0 + a1) + (a2 + a3);
    }
}

__global__ __launch_bounds__(64) void node_kernel(
    const float* __restrict__ x0, const float* __restrict__ W1,
    const float* __restrict__ b1, const float* __restrict__ W2,
    const float* __restrict__ b2, float* __restrict__ out)
{
    // Trp: 16 rows x 64 shorts (128B rows), within-wave transpose buffer.
    // W2f: 16 fragment-slabs x 64 lanes x 8 bf16 (16KB), snapshot A-operands.
    __shared__ __align__(16) unsigned short Trp[16 * 64];
    __shared__ __align__(16) unsigned short W2f[16 * 64 * 8];
    __shared__ __align__(16) float B2f[128];                 // 5*b2

    const int lane = threadIdx.x;       // 0..63 (one wave per block)
    const int n    = lane & 15;         // MFMA col == batch row within tile
    const int q    = lane >> 4;         // lane quad 0..3
    const int row  = (blockIdx.x << 4) + n;
    const int e    = n & 7;             // 16B-block XOR swizzle key

    // ---- stage W2 A-fragments + 5*b2 into LDS (single wave: in-order DS,
    // lgkmcnt-ordered, no barrier needed) ----
    for (int s = lane; s < 1024; s += 64) {
        const int f  = s >> 6;          // fragment id: mt8*2 + kt
        const int l  = s & 63;          // destination lane
        const int k0 = (f & 1) * 32 + (l >> 4) * 8;
        const int m  = (f >> 1) * 16 + (l & 15);
        uint4 wv;
        wv.x = pack2(W2[(k0 + 0) * 128 + m], W2[(k0 + 1) * 128 + m]);
        wv.y = pack2(W2[(k0 + 2) * 128 + m], W2[(k0 + 3) * 128 + m]);
        wv.z = pack2(W2[(k0 + 4) * 128 + m], W2[(k0 + 5) * 128 + m]);
        wv.w = pack2(W2[(k0 + 6) * 128 + m], W2[(k0 + 7) * 128 + m]);
        *reinterpret_cast<uint4*>(&W2f[s * 8]) = wv;
    }
    if (lane < 32) {
        floatx4 v = *reinterpret_cast<const floatx4*>(&b2[lane * 4]);
        floatx4 v5 = {5.f * v[0], 5.f * v[1], 5.f * v[2], 5.f * v[3]};
        *reinterpret_cast<floatx4*>(&B2f[lane * 4]) = v5;
    }

    // ---- persistent W21 A-fragments + c bias (C-layout) ----
    bf16x8 w21f[4][2];
    floatx4 cf[4];
    #pragma unroll
    for (int mt = 0; mt < 4; ++mt) {
        #pragma unroll
        for (int kt = 0; kt < 2; ++kt) {
            const int k0 = kt * 32 + q * 8;
            bf16x8 v;
            #pragma unroll
            for (int j = 0; j < 8; ++j)
                v[j] = f2bf(g_w21[(k0 + j) * 64 + mt * 16 + n]);
            w21f[mt][kt] = v;
        }
        cf[mt] = *reinterpret_cast<const floatx4*>(&g_w21[4096 + mt * 16 + q * 4]);
    }

    // ---- y state (C-layout: y[d=16*mt8+4q+r][b=row]) + t=0 snapshot ----
    floatx4 y[8];
    float* const outp = out + (size_t)row * (51 * 128);
    #pragma unroll
    for (int mt8 = 0; mt8 < 8; ++mt8) {
        y[mt8] = *reinterpret_cast<const floatx4*>(&x0[row * 256 + mt8 * 16 + q * 4]);
        *reinterpret_cast<floatx4*>(outp + mt8 * 16 + q * 4) = y[mt8];
    }

    // ---- z0 = y0 @ W1 + b1 (C-layout: z[h=16*mt+4q+r][b=row]) ----
    floatx4 z[4];
    #pragma unroll
    for (int mt = 0; mt < 4; ++mt)
        z[mt] = *reinterpret_cast<const floatx4*>(&b1[mt * 16 + q * 4]);
    #pragma unroll
    for (int kt = 0; kt < 4; ++kt) {
        floatx4 lo = *reinterpret_cast<const floatx4*>(&x0[row * 256 + kt * 32 + q * 8]);
        floatx4 hi = *reinterpret_cast<const floatx4*>(&x0[row * 256 + kt * 32 + q * 8 + 4]);
        bf16x8 yb;
        yb[0] = f2bf(lo[0]); yb[1] = f2bf(lo[1]); yb[2] = f2bf(lo[2]); yb[3] = f2bf(lo[3]);
        yb[4] = f2bf(hi[0]); yb[5] = f2bf(hi[1]); yb[6] = f2bf(hi[2]); yb[7] = f2bf(hi[3]);
        #pragma unroll
        for (int mt = 0; mt < 4; ++mt) {
            const int k0 = kt * 32 + q * 8;
            bf16x8 wf;
            #pragma unroll
            for (int j = 0; j < 8; ++j)
                wf[j] = f2bf(W1[(k0 + j) * 64 + mt * 16 + n]);
            z[mt] = __builtin_amdgcn_mfma_f32_16x16x32_bf16(wf, yb, z[mt], 0, 0, 0);
        }
    }

    floatx4 S[4];
    #pragma unroll
    for (int mt = 0; mt < 4; ++mt) S[mt] = floatx4{0.f, 0.f, 0.f, 0.f};

    // Transpose-buffer byte offsets (both sides XOR-swizzle 16B blocks by e):
    // write b64 -> words 8mt+2q (pairs for h=16mt+4q..+3 of column n)
    // read  b128 -> words 16kt+4q..+3 == B-frag k = 32kt+8q+j, j=0..7
    char* const trp = reinterpret_cast<char*>(Trp);
    int wr[4], rd[2];
    #pragma unroll
    for (int mt = 0; mt < 4; ++mt)
        wr[mt] = n * 128 + (((2 * mt + (q >> 1)) ^ e) * 16) + (q & 1) * 8;
    rd[0] = n * 128 + ((q ^ e) * 16);
    rd[1] = n * 128 + (((4 + q) ^ e) * 16);

    for (int ti = 1; ti <= 50; ++ti) {
        #pragma unroll
        for (int ss = 0; ss < 5; ++ss) {
            // a = tanh(z); S += a; pack pairs; within-wave transpose via LDS
            #pragma unroll
            for (int mt = 0; mt < 4; ++mt) {
                float a0 = tanh_fast(z[mt][0]);
                float a1 = tanh_fast(z[mt][1]);
                float a2 = tanh_fast(z[mt][2]);
                float a3 = tanh_fast(z[mt][3]);
                S[mt][0] += a0; S[mt][1] += a1; S[mt][2] += a2; S[mt][3] += a3;
                uint2 p; p.x = pack2(a0, a1); p.y = pack2(a2, a3);
                *reinterpret_cast<uint2*>(trp + wr[mt]) = p;
            }
            bf16x8 af0 = *reinterpret_cast<const bf16x8*>(trp + rd[0]);
            bf16x8 af1 = *reinterpret_cast<const bf16x8*>(trp + rd[1]);

            // z += DT*(a @ W21 + c): 4 independent 2-deep MFMA chains
            #pragma unroll
            for (int mt = 0; mt < 4; ++mt) {
                floatx4 acc = cf[mt];
                acc = __builtin_amdgcn_mfma_f32_16x16x32_bf16(w21f[mt][0], af0, acc, 0, 0, 0);
                acc = __builtin_amdgcn_mfma_f32_16x16x32_bf16(w21f[mt][1], af1, acc, 0, 0, 0);
                #pragma unroll
                for (int r = 0; r < 4; ++r)
                    z[mt][r] = fmaf(0.001f, acc[r], z[mt][r]);
            }
        }

        // ---- snapshot: y += DT*(S @ W2 + 5 b2); store; reset S ----
        #pragma unroll
        for (int mt = 0; mt < 4; ++mt) {
            uint2 p; p.x = pack2(S[mt][0], S[mt][1]); p.y = pack2(S[mt][2], S[mt][3]);
            *reinterpret_cast<uint2*>(trp + wr[mt]) = p;
            S[mt] = floatx4{0.f, 0.f, 0.f, 0.f};
        }
        bf16x8 sf0 = *reinterpret_cast<const bf16x8*>(trp + rd[0]);
        bf16x8 sf1 = *reinterpret_cast<const bf16x8*>(trp + rd[1]);
        float* const o = outp + ti * 128;
        #pragma unroll
        for (int mt8 = 0; mt8 < 8; ++mt8) {
            floatx4 acc = *reinterpret_cast<const floatx4*>(&B2f[mt8 * 16 + q * 4]);
            bf16x8 wa = *reinterpret_cast<const bf16x8*>(&W2f[(mt8 * 2 + 0) * 512 + lane * 8]);
            bf16x8 wb = *reinterpret_cast<const bf16x8*>(&W2f[(mt8 * 2 + 1) * 512 + lane * 8]);
            acc = __builtin_amdgcn_mfma_f32_16x16x32_bf16(wa, sf0, acc, 0, 0, 0);
            acc = __builtin_amdgcn_mfma_f32_16x16x32_bf16(wb, sf1, acc, 0, 0, 0);
            #pragma unroll
            for (int r = 0; r < 4; ++r)
                y[mt8][r] = fmaf(0.001f, acc[r], y[mt8][r]);
            *reinterpret_cast<floatx4*>(o + mt8 * 16 + q * 4) = y[mt8];
        }
    }
}

extern "C" void kernel_launch(void* const* d_in, const int* in_sizes, int n_in,
                              void* d_out, int out_size, void* d_ws, size_t ws_size,
                              hipStream_t stream) {
    const float* x0 = (const float*)d_in[0];
    // d_in[1] = t grid: fixed 51 outputs x 5 substeps, unused
    const float* W1 = (const float*)d_in[2];
    const float* b1 = (const float*)d_in[3];
    const float* W2 = (const float*)d_in[4];
    const float* b2 = (const float*)d_in[5];
    float* out = (float*)d_out;

    precompute_kernel<<<dim3(65), dim3(64), 0, stream>>>(W1, W2, b2);
    node_kernel<<<dim3(512), dim3(64), 0, stream>>>(x0, W1, b1, W2, b2, out);
}

// Round 5
// 313.110 us; speedup vs baseline: 1.0861x; 1.0861x over previous
//
#include <hip/hip_runtime.h>
#include <hip/hip_bf16.h>

// NeuralODE: y_{s+1} = y_s + DT*(tanh(y W1 + b1) W2 + b2), 250 steps,
// snapshot every 5 -> out[8192][51][128] fp32.
//
// R4: hidden-space recurrence: z = y W1 + b1, W21 = W2 W1 (fp32 prologue),
//   substep:  a = tanh(z); z += DT*(a @ W21 + c),  c = b2 W1
//   interval: y += DT*(S @ W2 + 5 b2), S = sum of 5 a's
// R5: barrier-free single-wave design (one wave owns a 16-row tile + the
//   full 64-dim hidden state); LDS round-trip transpose sat on the chain.
// R6: permlane transpose -- FAILED (absmax 0.515): raw-asm permlane swap
//   semantics/hazards unverifiable here.
// R7: TRANSPOSE-FREE via hidden-basis relabeling. The C-layout (mt,q,r) ->
// B-layout (kt,q,j) mismatch is a pure permutation of the hidden index h.
// Relabel: T(16mt+4q+r) = 32*(mt>>1) + 8q + (mt&1)*4 + r (bijection).
// Load W21's OUTPUT columns (and c, b1, W1's output cols) in T-order; keep
// the reduction side s = hin = identity. Then MFMA C-output slot (mt,q,r)
// IS B-operand slot (kt=mt>>1, j=(mt&1)*4+r): tanh/pack/Euler are pure
// per-lane register ops. No LDS, no cross-lane, no barrier in the substep.
// Reduction order unchanged -> bitwise identical values to R5 (passed).

typedef __attribute__((ext_vector_type(8))) short bf16x8;   // 8 bf16 = 4 VGPRs
typedef __attribute__((ext_vector_type(4))) float floatx4;

__device__ float g_w21[64 * 64 + 64];   // W21[hin][hout] (64x64) then c[hout]

static __device__ __forceinline__ short f2bf(float f) {
    return __builtin_bit_cast(short, (__bf16)f);            // RNE, HW cvt
}

static __device__ __forceinline__ unsigned pack2(float a, float b) {
    unsigned short lo = __builtin_bit_cast(unsigned short, (__bf16)a);
    unsigned short hi = __builtin_bit_cast(unsigned short, (__bf16)b);
    return (unsigned)lo | ((unsigned)hi << 16);
}

static __device__ __forceinline__ float tanh_fast(float x) {
    // tanh(x) = 1 - 2/(1+e^{2x}); exp->inf saturates to +1, exp->0 to -1.
    float e = __expf(2.0f * x);
    return 1.0f - 2.0f * __builtin_amdgcn_rcpf(1.0f + e);
}

// ---- prologue: W21 = W2 @ W1 (fp32), c = b2 @ W1 ----
__global__ __launch_bounds__(64) void precompute_kernel(
    const float* __restrict__ W1, const float* __restrict__ W2,
    const float* __restrict__ b2)
{
    const int hout = threadIdx.x;   // 0..63
    const int hin  = blockIdx.x;    // 0..64 (64 == bias row)
    float a0 = 0.f, a1 = 0.f, a2 = 0.f, a3 = 0.f;
    if (hin < 64) {
        #pragma unroll 4
        for (int d = 0; d < 128; d += 4) {
            a0 = fmaf(W2[hin * 128 + d + 0], W1[(d + 0) * 64 + hout], a0);
            a1 = fmaf(W2[hin * 128 + d + 1], W1[(d + 1) * 64 + hout], a1);
            a2 = fmaf(W2[hin * 128 + d + 2], W1[(d + 2) * 64 + hout], a2);
            a3 = fmaf(W2[hin * 128 + d + 3], W1[(d + 3) * 64 + hout], a3);
        }
        g_w21[hin * 64 + hout] = (a0 + a1) + (a2 + a3);
    } else {
        #pragma unroll 4
        for (int d = 0; d < 128; d += 4) {
            a0 = fmaf(b2[d + 0], W1[(d + 0) * 64 + hout], a0);
            a1 = fmaf(b2[d + 1], W1[(d + 1) * 64 + hout], a1);
            a2 = fmaf(b2[d + 2], W1[(d + 2) * 64 + hout], a2);
            a3 = fmaf(b2[d + 3], W1[(d + 3) * 64 + hout], a3);
        }
        g_w21[4096 + hout] = (a0 + a1) + (a2 + a3);
    }
}

__global__ __launch_bounds__(64) void node_kernel(
    const float* __restrict__ x0, const float* __restrict__ W1,
    const float* __restrict__ b1, const float* __restrict__ W2,
    const float* __restrict__ b2, float* __restrict__ out)
{
    // W2f: 16 fragment-slabs x 64 lanes x 8 bf16 (16KB), snapshot A-operands.
    __shared__ __align__(16) unsigned short W2f[16 * 64 * 8];
    __shared__ __align__(16) float B2f[128];                 // 5*b2

    const int lane = threadIdx.x;       // 0..63 (one wave per block)
    const int n    = lane & 15;         // MFMA col == batch row within tile
    const int q    = lane >> 4;         // lane quad 0..3
    const int row  = (blockIdx.x << 4) + n;

    // ---- stage W2 A-fragments + 5*b2 into LDS (single wave: in-order DS,
    // lgkmcnt-ordered, no barrier needed). Reduction index k = hin slot =
    // identity, so W2 rows are NOT permuted (same as passing R5 code). ----
    for (int s = lane; s < 1024; s += 64) {
        const int f  = s >> 6;          // fragment id: mt8*2 + kt
        const int l  = s & 63;          // destination lane
        const int k0 = (f & 1) * 32 + (l >> 4) * 8;
        const int m  = (f >> 1) * 16 + (l & 15);
        uint4 wv;
        wv.x = pack2(W2[(k0 + 0) * 128 + m], W2[(k0 + 1) * 128 + m]);
        wv.y = pack2(W2[(k0 + 2) * 128 + m], W2[(k0 + 3) * 128 + m]);
        wv.z = pack2(W2[(k0 + 4) * 128 + m], W2[(k0 + 5) * 128 + m]);
        wv.w = pack2(W2[(k0 + 6) * 128 + m], W2[(k0 + 7) * 128 + m]);
        *reinterpret_cast<uint4*>(&W2f[s * 8]) = wv;
    }
    if (lane < 32) {
        floatx4 v = *reinterpret_cast<const floatx4*>(&b2[lane * 4]);
        floatx4 v5 = {5.f * v[0], 5.f * v[1], 5.f * v[2], 5.f * v[3]};
        *reinterpret_cast<floatx4*>(&B2f[lane * 4]) = v5;
    }

    // ---- persistent W21 A-fragments + c bias, hout in T-order ----
    // T(16mt+4qq+rr) = 32*(mt>>1) + 8*qq + (mt&1)*4 + rr
    bf16x8 w21f[4][2];
    floatx4 cf[4];
    #pragma unroll
    for (int mt = 0; mt < 4; ++mt) {
        const int hout = 32 * (mt >> 1) + 8 * (n >> 2) + (mt & 1) * 4 + (n & 3);
        #pragma unroll
        for (int kt = 0; kt < 2; ++kt) {
            const int k0 = kt * 32 + q * 8;
            bf16x8 v;
            #pragma unroll
            for (int j = 0; j < 8; ++j)
                v[j] = f2bf(g_w21[(k0 + j) * 64 + hout]);
            w21f[mt][kt] = v;
        }
        #pragma unroll
        for (int r = 0; r < 4; ++r)
            cf[mt][r] = g_w21[4096 + 32 * (mt >> 1) + 8 * q + (mt & 1) * 4 + r];
    }

    // ---- y state (C-layout: y[d=16*mt8+4q+r][b=row]) + t=0 snapshot ----
    floatx4 y[8];
    float* const outp = out + (size_t)row * (51 * 128);
    #pragma unroll
    for (int mt8 = 0; mt8 < 8; ++mt8) {
        y[mt8] = *reinterpret_cast<const floatx4*>(&x0[row * 256 + mt8 * 16 + q * 4]);
        *reinterpret_cast<floatx4*>(outp + mt8 * 16 + q * 4) = y[mt8];
    }

    // ---- z0 = y0 @ W1 + b1, output slots in T-order ----
    // z[mt][r] == B-slot (kt=mt>>1, q, j=(mt&1)*4+r), true h = T(16mt+4q+r)
    floatx4 z[4];
    #pragma unroll
    for (int mt = 0; mt < 4; ++mt)
        #pragma unroll
        for (int r = 0; r < 4; ++r)
            z[mt][r] = b1[32 * (mt >> 1) + 8 * q + (mt & 1) * 4 + r];
    #pragma unroll
    for (int kt = 0; kt < 4; ++kt) {
        floatx4 lo = *reinterpret_cast<const floatx4*>(&x0[row * 256 + kt * 32 + q * 8]);
        floatx4 hi = *reinterpret_cast<const floatx4*>(&x0[row * 256 + kt * 32 + q * 8 + 4]);
        bf16x8 yb;
        yb[0] = f2bf(lo[0]); yb[1] = f2bf(lo[1]); yb[2] = f2bf(lo[2]); yb[3] = f2bf(lo[3]);
        yb[4] = f2bf(hi[0]); yb[5] = f2bf(hi[1]); yb[6] = f2bf(hi[2]); yb[7] = f2bf(hi[3]);
        #pragma unroll
        for (int mt = 0; mt < 4; ++mt) {
            const int hout = 32 * (mt >> 1) + 8 * (n >> 2) + (mt & 1) * 4 + (n & 3);
            const int k0 = kt * 32 + q * 8;
            bf16x8 wf;
            #pragma unroll
            for (int j = 0; j < 8; ++j)
                wf[j] = f2bf(W1[(k0 + j) * 64 + hout]);
            z[mt] = __builtin_amdgcn_mfma_f32_16x16x32_bf16(wf, yb, z[mt], 0, 0, 0);
        }
    }

    floatx4 S[4];
    #pragma unroll
    for (int mt = 0; mt < 4; ++mt) S[mt] = floatx4{0.f, 0.f, 0.f, 0.f};

    for (int ti = 1; ti <= 50; ++ti) {
        #pragma unroll
        for (int ss = 0; ss < 5; ++ss) {
            // a = tanh(z) elementwise; S += a (all slots are B-aligned)
            floatx4 a[4];
            #pragma unroll
            for (int mt = 0; mt < 4; ++mt) {
                #pragma unroll
                for (int r = 0; r < 4; ++r) {
                    a[mt][r] = tanh_fast(z[mt][r]);
                    S[mt][r] += a[mt][r];
                }
            }
            // pack: af[kt] elem j: j<4 from a[2kt][j], j>=4 from a[2kt+1][j-4]
            uint4 w0 = { pack2(a[0][0], a[0][1]), pack2(a[0][2], a[0][3]),
                         pack2(a[1][0], a[1][1]), pack2(a[1][2], a[1][3]) };
            uint4 w1v = { pack2(a[2][0], a[2][1]), pack2(a[2][2], a[2][3]),
                          pack2(a[3][0], a[3][1]), pack2(a[3][2], a[3][3]) };
            bf16x8 af0 = __builtin_bit_cast(bf16x8, w0);
            bf16x8 af1 = __builtin_bit_cast(bf16x8, w1v);

            // z += DT*(a @ W21 + c): 4 independent 2-deep MFMA chains
            #pragma unroll
            for (int mt = 0; mt < 4; ++mt) {
                floatx4 acc = cf[mt];
                acc = __builtin_amdgcn_mfma_f32_16x16x32_bf16(w21f[mt][0], af0, acc, 0, 0, 0);
                acc = __builtin_amdgcn_mfma_f32_16x16x32_bf16(w21f[mt][1], af1, acc, 0, 0, 0);
                #pragma unroll
                for (int r = 0; r < 4; ++r)
                    z[mt][r] = fmaf(0.001f, acc[r], z[mt][r]);
            }
        }

        // ---- snapshot: y += DT*(S @ W2 + 5 b2); store; reset S ----
        uint4 sw0 = { pack2(S[0][0], S[0][1]), pack2(S[0][2], S[0][3]),
                      pack2(S[1][0], S[1][1]), pack2(S[1][2], S[1][3]) };
        uint4 sw1 = { pack2(S[2][0], S[2][1]), pack2(S[2][2], S[2][3]),
                      pack2(S[3][0], S[3][1]), pack2(S[3][2], S[3][3]) };
        bf16x8 sf0 = __builtin_bit_cast(bf16x8, sw0);
        bf16x8 sf1 = __builtin_bit_cast(bf16x8, sw1);
        #pragma unroll
        for (int mt = 0; mt < 4; ++mt) S[mt] = floatx4{0.f, 0.f, 0.f, 0.f};

        float* const o = outp + ti * 128;
        #pragma unroll
        for (int mt8 = 0; mt8 < 8; ++mt8) {
            floatx4 acc = *reinterpret_cast<const floatx4*>(&B2f[mt8 * 16 + q * 4]);
            bf16x8 wa = *reinterpret_cast<const bf16x8*>(&W2f[(mt8 * 2 + 0) * 512 + lane * 8]);
            bf16x8 wb = *reinterpret_cast<const bf16x8*>(&W2f[(mt8 * 2 + 1) * 512 + lane * 8]);
            acc = __builtin_amdgcn_mfma_f32_16x16x32_bf16(wa, sf0, acc, 0, 0, 0);
            acc = __builtin_amdgcn_mfma_f32_16x16x32_bf16(wb, sf1, acc, 0, 0, 0);
            #pragma unroll
            for (int r = 0; r < 4; ++r)
                y[mt8][r] = fmaf(0.001f, acc[r], y[mt8][r]);
            *reinterpret_cast<floatx4*>(o + mt8 * 16 + q * 4) = y[mt8];
        }
    }
}

extern "C" void kernel_launch(void* const* d_in, const int* in_sizes, int n_in,
                              void* d_out, int out_size, void* d_ws, size_t ws_size,
                              hipStream_t stream) {
    const float* x0 = (const float*)d_in[0];
    // d_in[1] = t grid: fixed 51 outputs x 5 substeps, unused
    const float* W1 = (const float*)d_in[2];
    const float* b1 = (const float*)d_in[3];
    const float* W2 = (const float*)d_in[4];
    const float* b2 = (const float*)d_in[5];
    float* out = (float*)d_out;

    precompute_kernel<<<dim3(65), dim3(64), 0, stream>>>(W1, W2, b2);
    node_kernel<<<dim3(512), dim3(64), 0, stream>>>(x0, W1, b1, W2, b2, out);
}